// Round 3
// baseline (449.350 us; speedup 1.0000x reference)
//
#include <hip/hip_runtime.h>
#include <hip/hip_cooperative_groups.h>
#include <cstdint>

namespace cg = cooperative_groups;
typedef unsigned long long u64;

#define THRESH 0.5f
#define SIGMA 2.0f
#define TPB 64      // pair-tile dim (64x64 pairs per tile task, 4x4 per thread)
#define NSPLIT 8    // K splits per tile
#define CH 64       // u64 words staged per chunk per mask row
#define CST 66      // padded LDS row stride in u64 (2-row bank shift -> <=2-way, free)

union SharedU {
    u64 sm[2 * TPB][CST];                 // 67,584 B — phase P3
    struct { double ls[4]; int lc[4]; } red;  // P1 block reduce
    float lmx[4];                         // P4/P5 block max reduce
};

// ---------------------------------------------------------------------------
// One cooperative kernel, 6 phases, 5 grid syncs. Replaces 6 kernels + memset
// (7 graph nodes) with 1 node to eliminate inter-node replay gaps.
// ---------------------------------------------------------------------------
__global__ __launch_bounds__(256, 2) void k_mega(
    const float* __restrict__ preds, const float* __restrict__ cate,
    const int* __restrict__ labels,
    u64* __restrict__ packed, double* __restrict__ pssum, int* __restrict__ pcnt,
    float* __restrict__ scoreBuf, float* __restrict__ sumBuf,
    float* __restrict__ sScore, float* __restrict__ sSum,
    int* __restrict__ sLabel, int* __restrict__ order,
    float* __restrict__ comp, unsigned* __restrict__ part8,
    float* __restrict__ out, int N, int HW)
{
    cg::grid_group grid = cg::this_grid();
    __shared__ SharedU sh;
    const int tid = threadIdx.x;
    const int wave = tid >> 6, lane = tid & 63;
    const int WORDS = HW >> 6;

    // ---- P1: binarize + bit-pack (64-lane ballot) + partial soft-score sums.
    // Tasks = (mask i, quarter sub); 2 outstanding float4 loads for latency.
    {
        const int seg = HW >> 2;
        const int iters = seg >> 10;             // 1024 px per k-iter
        for (int task = blockIdx.x; task < N * 4; task += gridDim.x) {
            const int i = task >> 2, sub = task & 3;
            const float* src = preds + (size_t)i * HW + (size_t)sub * seg;
            u64* dst = packed + (size_t)i * WORDS + (size_t)sub * (seg >> 6);
            double ssum = 0.0;
            int cnt = 0;
            for (int k = 0; k < iters; k += 2) {
                const int p0 = (k << 10) + (wave << 8) + (lane << 2);
                const float4 v0 = *reinterpret_cast<const float4*>(src + p0);
                const float4 v1 = *reinterpret_cast<const float4*>(src + p0 + 1024);
                const bool a0 = v0.x > THRESH, a1 = v0.y > THRESH, a2 = v0.z > THRESH, a3 = v0.w > THRESH;
                const bool b0 = v1.x > THRESH, b1 = v1.y > THRESH, b2 = v1.z > THRESH, b3 = v1.w > THRESH;
                const u64 ma0 = __ballot(a0), ma1 = __ballot(a1), ma2 = __ballot(a2), ma3 = __ballot(a3);
                const u64 mb0 = __ballot(b0), mb1 = __ballot(b1), mb2 = __ballot(b2), mb3 = __ballot(b3);
                if (lane < 4) {
                    const u64 ma = (lane == 0) ? ma0 : (lane == 1) ? ma1 : (lane == 2) ? ma2 : ma3;
                    const u64 mb = (lane == 0) ? mb0 : (lane == 1) ? mb1 : (lane == 2) ? mb2 : mb3;
                    dst[(k << 4) + (wave << 2) + lane] = ma;
                    dst[((k + 1) << 4) + (wave << 2) + lane] = mb;
                }
                cnt += (int)a0 + (int)a1 + (int)a2 + (int)a3
                     + (int)b0 + (int)b1 + (int)b2 + (int)b3;
                ssum += (a0 ? (double)v0.x : 0.0) + (a1 ? (double)v0.y : 0.0)
                      + (a2 ? (double)v0.z : 0.0) + (a3 ? (double)v0.w : 0.0)
                      + (b0 ? (double)v1.x : 0.0) + (b1 ? (double)v1.y : 0.0)
                      + (b2 ? (double)v1.z : 0.0) + (b3 ? (double)v1.w : 0.0);
            }
            for (int off = 32; off > 0; off >>= 1) {
                ssum += __shfl_down(ssum, off);
                cnt  += __shfl_down(cnt, off);
            }
            if (lane == 0) { sh.red.ls[wave] = ssum; sh.red.lc[wave] = cnt; }
            __syncthreads();
            if (tid == 0) {
                pssum[task] = sh.red.ls[0] + sh.red.ls[1] + sh.red.ls[2] + sh.red.ls[3];
                pcnt[task]  = sh.red.lc[0] + sh.red.lc[1] + sh.red.lc[2] + sh.red.lc[3];
            }
            __syncthreads();
        }
    }
    grid.sync();

    // ---- P2a: finalize per-mask score from the 4 quarter-partials.
    for (int i = blockIdx.x * 256 + tid; i < N; i += gridDim.x * 256) {
        const double S = pssum[4*i] + pssum[4*i+1] + pssum[4*i+2] + pssum[4*i+3];
        const int C = pcnt[4*i] + pcnt[4*i+1] + pcnt[4*i+2] + pcnt[4*i+3];
        scoreBuf[i] = cate[i] * (float)(S / (double)(C > 1 ? C : 1));
        sumBuf[i] = (float)C;
    }
    grid.sync();

    // ---- P2b: rank sort (descending, stable ties by original index).
    for (int i = blockIdx.x * 256 + tid; i < N; i += gridDim.x * 256) {
        const float si = scoreBuf[i];
        int r = 0;
        for (int j = 0; j < N; ++j) {
            const float sj = scoreBuf[j];
            r += (sj > si) || (sj == si && j < i);
        }
        order[r] = i;
        sScore[r] = si;
        sSum[r] = sumBuf[i];
        sLabel[r] = labels[i];
    }
    grid.sync();

    // ---- P3: pairwise intersections. Upper-tri 64x64 tiles x 8 K-splits;
    // 16x16 threads with 4x4 register sub-tiles; non-atomic per-split partials
    // part8[pair*8+split] (every slot of every valid pair written exactly once).
    {
        const int NT = (N + TPB - 1) / TPB;
        const int ntri = NT * (NT + 1) / 2;
        const int kwords = WORDS / NSPLIT;
        const int a = tid >> 4, bb = tid & 15;
        for (int task = blockIdx.x; task < ntri * NSPLIT; task += gridDim.x) {
            const int split = task / ntri;
            int b = task - split * ntri;
            int ti = 0, rowlen = NT;
            while (b >= rowlen) { b -= rowlen; ++ti; --rowlen; }
            const int tj = ti + b;
            const int kbase = split * kwords;

            unsigned acc[4][4] = {};
            for (int c = 0; c < kwords / CH; ++c) {
                const int base = kbase + c * CH;
                for (int idx = tid; idx < 2 * TPB * (CH / 2); idx += 256) {
                    const int ml = idx >> 5;
                    const int w = (idx & 31) << 1;
                    const int g = (ml < TPB) ? (ti * TPB + ml) : (tj * TPB + (ml - TPB));
                    u64 x0 = 0, x1 = 0;
                    if (g < N) {
                        const u64* p = packed + (size_t)order[g] * WORDS + base + w;
                        x0 = p[0];
                        x1 = p[1];
                    }
                    sh.sm[ml][w] = x0;
                    sh.sm[ml][w + 1] = x1;
                }
                __syncthreads();
                #pragma unroll 2
                for (int w = 0; w < CH; w += 2) {
                    u64 pi0[4], pi1[4], pj0[4], pj1[4];
                    #pragma unroll
                    for (int t = 0; t < 4; ++t) { pi0[t] = sh.sm[4*a + t][w]; pi1[t] = sh.sm[4*a + t][w + 1]; }
                    #pragma unroll
                    for (int s = 0; s < 4; ++s) { pj0[s] = sh.sm[TPB + 4*bb + s][w]; pj1[s] = sh.sm[TPB + 4*bb + s][w + 1]; }
                    #pragma unroll
                    for (int t = 0; t < 4; ++t)
                        #pragma unroll
                        for (int s = 0; s < 4; ++s)
                            acc[t][s] += (unsigned)__popcll(pi0[t] & pj0[s])
                                       + (unsigned)__popcll(pi1[t] & pj1[s]);
                }
                __syncthreads();
            }
            #pragma unroll
            for (int t = 0; t < 4; ++t)
                #pragma unroll
                for (int s = 0; s < 4; ++s) {
                    const int gi = ti * TPB + 4*a + t;
                    const int gj = tj * TPB + 4*bb + s;
                    if (gj < N && gi < gj)
                        part8[((size_t)gi * N + gj) * NSPLIT + split] = acc[t][s];
                }
        }
    }
    grid.sync();

    // ---- P4: comp[c] = max_{k<c, label match} iou(k,c); fold 8 split partials
    // (32B contiguous per pair -> two uint4 loads).
    for (int c = blockIdx.x; c < N; c += gridDim.x) {
        const float suc = sSum[c];
        const int lc_ = sLabel[c];
        float m = 0.0f;
        for (int k = tid; k < c; k += 256) {
            if (sLabel[k] == lc_) {
                const uint4* p = reinterpret_cast<const uint4*>(part8 + ((size_t)k * N + c) * NSPLIT);
                const uint4 q0 = p[0], q1 = p[1];
                const float inter = (float)(q0.x + q0.y + q0.z + q0.w + q1.x + q1.y + q1.z + q1.w);
                const float un = sSum[k] + suc - inter;
                m = fmaxf(m, inter / fmaxf(un, 1.0f));
            }
        }
        for (int off = 32; off > 0; off >>= 1) m = fmaxf(m, __shfl_down(m, off));
        if (lane == 0) sh.lmx[wave] = m;
        __syncthreads();
        if (tid == 0) comp[c] = fmaxf(fmaxf(sh.lmx[0], sh.lmx[1]), fmaxf(sh.lmx[2], sh.lmx[3]));
        __syncthreads();
    }
    grid.sync();

    // ---- P5: out[j] = sScore[j] * exp(-sigma * max_i(d_ij^2 - comp[i]^2)),
    // d_ij = (i<j && label match) ? iou(i,j) : 0.
    for (int j = blockIdx.x; j < N; j += gridDim.x) {
        const float suj = sSum[j];
        const int lj = sLabel[j];
        float m = -3.0e38f;
        for (int i = tid; i < N; i += 256) {
            const float ci = comp[i];
            float d = 0.0f;
            if (i < j && sLabel[i] == lj) {
                const uint4* p = reinterpret_cast<const uint4*>(part8 + ((size_t)i * N + j) * NSPLIT);
                const uint4 q0 = p[0], q1 = p[1];
                const float inter = (float)(q0.x + q0.y + q0.z + q0.w + q1.x + q1.y + q1.z + q1.w);
                const float un = sSum[i] + suj - inter;
                d = inter / fmaxf(un, 1.0f);
            }
            m = fmaxf(m, d * d - ci * ci);
        }
        for (int off = 32; off > 0; off >>= 1) m = fmaxf(m, __shfl_down(m, off));
        if (lane == 0) sh.lmx[wave] = m;
        __syncthreads();
        if (tid == 0) {
            const float mm = fmaxf(fmaxf(sh.lmx[0], sh.lmx[1]), fmaxf(sh.lmx[2], sh.lmx[3]));
            out[j] = sScore[j] * expf(-SIGMA * mm);
        }
        __syncthreads();
    }
}

extern "C" void kernel_launch(void* const* d_in, const int* in_sizes, int n_in,
                              void* d_out, int out_size, void* d_ws, size_t ws_size,
                              hipStream_t stream)
{
    const float* preds  = (const float*)d_in[0];
    const float* cate   = (const float*)d_in[1];
    const int*   labels = (const int*)d_in[2];
    float* out = (float*)d_out;

    int N = in_sizes[1];
    int HW = in_sizes[0] / N;
    const int WORDS = HW >> 6;

    char* ws = (char*)d_ws;
    size_t off = 0;
    auto take = [&](size_t bytes) -> void* {
        void* p = ws + off;
        off = (off + bytes + 255) & ~(size_t)255;
        return p;
    };
    u64*      packed   = (u64*)     take((size_t)N * WORDS * sizeof(u64));       // ~4.1 MB
    double*   pssum    = (double*)  take((size_t)N * 4 * sizeof(double));
    int*      pcnt     = (int*)     take((size_t)N * 4 * sizeof(int));
    float*    scoreBuf = (float*)   take((size_t)N * sizeof(float));
    float*    sumBuf   = (float*)   take((size_t)N * sizeof(float));
    float*    sScore   = (float*)   take((size_t)N * sizeof(float));
    float*    sSum     = (float*)   take((size_t)N * sizeof(float));
    int*      sLabel   = (int*)     take((size_t)N * sizeof(int));
    int*      order    = (int*)     take((size_t)N * sizeof(int));
    float*    comp     = (float*)   take((size_t)N * sizeof(float));
    unsigned* part8    = (unsigned*)take((size_t)N * N * NSPLIT * sizeof(unsigned)); // ~8 MB
    (void)ws_size; (void)n_in; (void)out_size;

    // Co-residency cap: LDS 67.6 KB -> 2 blocks/CU -> 512 blocks on 256 CUs.
    int occ = 0;
    if (hipOccupancyMaxActiveBlocksPerMultiprocessor(&occ, k_mega, 256, 0) != hipSuccess || occ < 1)
        occ = 2;
    int gridBlocks = occ * 256;
    if (gridBlocks > 2048) gridBlocks = 2048;

    void* args[] = {
        (void*)&preds, (void*)&cate, (void*)&labels,
        (void*)&packed, (void*)&pssum, (void*)&pcnt,
        (void*)&scoreBuf, (void*)&sumBuf,
        (void*)&sScore, (void*)&sSum, (void*)&sLabel, (void*)&order,
        (void*)&comp, (void*)&part8, (void*)&out, (void*)&N, (void*)&HW
    };
    hipLaunchCooperativeKernel(k_mega, dim3(gridBlocks), dim3(256), args, 0, stream);
}

// Round 4
// 245.502 us; speedup vs baseline: 1.8303x; 1.8303x over previous
//
#include <hip/hip_runtime.h>
#include <cstdint>

typedef unsigned long long u64;

#define THRESH 0.5f
#define SIGMA 2.0f
#define TPB 64      // pair-tile dim (64x64 pairs per tile)
#define NSPLIT 16   // K splits per tile (1024 words / 16 = 64-word chunks)
#define CST 66      // LDS row stride (u64): 528B rows -> 16B aligned, reads <=2-way (free)

// better(a,b): does a precede b in the reference's sort order?
// argsort(-scores) is stable -> descending score, ties by original index.
__device__ __forceinline__ bool better(float sa, int a, float sb, int b) {
    return (sa > sb) || (sa == sb && a < b);
}

// ---------------------------------------------------------------------------
// K1: one 512-thread block per mask. Binarize + bit-pack via 64-lane __ballot
// (fixed pixel permutation, identical for all masks -> popcount(AND) exact),
// fp64 soft-score accumulation, writes FINAL score/sum (no finalize node).
// ---------------------------------------------------------------------------
__global__ __launch_bounds__(512) void k_pack(
    const float* __restrict__ preds, const float* __restrict__ cate,
    u64* __restrict__ packed, float* __restrict__ score, float* __restrict__ sum,
    int HW)
{
    const int i = blockIdx.x;
    const float* src = preds + (size_t)i * HW;
    u64* dst = packed + (size_t)i * (HW >> 6);
    const int tid = threadIdx.x;
    const int wave = tid >> 6, lane = tid & 63;
    double ssum = 0.0;
    int cnt = 0;
    const int iters = HW >> 11;                  // 2048 px per block-iter
    for (int k = 0; k < iters; ++k) {
        const int p = (k << 11) + (wave << 8) + (lane << 2);
        const float4 v = *reinterpret_cast<const float4*>(src + p);
        const bool b0 = v.x > THRESH, b1 = v.y > THRESH, b2 = v.z > THRESH, b3 = v.w > THRESH;
        const u64 m0 = __ballot(b0);
        const u64 m1 = __ballot(b1);
        const u64 m2 = __ballot(b2);
        const u64 m3 = __ballot(b3);
        if (lane < 4) {
            const u64 m = (lane == 0) ? m0 : (lane == 1) ? m1 : (lane == 2) ? m2 : m3;
            dst[(k << 5) + (wave << 2) + lane] = m;
        }
        cnt += (int)b0 + (int)b1 + (int)b2 + (int)b3;
        ssum += (b0 ? (double)v.x : 0.0) + (b1 ? (double)v.y : 0.0)
              + (b2 ? (double)v.z : 0.0) + (b3 ? (double)v.w : 0.0);
    }
    for (int off = 32; off > 0; off >>= 1) {
        ssum += __shfl_down(ssum, off);
        cnt  += __shfl_down(cnt, off);
    }
    __shared__ double ls[8];
    __shared__ int lc[8];
    if (lane == 0) { ls[wave] = ssum; lc[wave] = cnt; }
    __syncthreads();
    if (tid == 0) {
        double S = 0.0; int C = 0;
        #pragma unroll
        for (int w = 0; w < 8; ++w) { S += ls[w]; C += lc[w]; }
        score[i] = cate[i] * (float)(S / (double)(C > 1 ? C : 1));
        sum[i] = (float)C;
    }
}

// ---------------------------------------------------------------------------
// K2: pairwise intersections on UNSORTED pairs (inter is symmetric; order is
// applied logically via better() downstream). Grid (ntri, NSPLIT). 16x16
// threads, 4x4 register sub-tiles. i-rows blocked (4a+t, broadcast reads),
// j-rows cyclic (bb+16s): with CST=66 both read patterns are <=2-way (free).
// Non-atomic per-split partials: part[(gi*N+gj)*NSPLIT+split], each valid
// slot written exactly once (no memset node needed).
// ---------------------------------------------------------------------------
__global__ __launch_bounds__(256) void k_inter(
    const u64* __restrict__ packed, unsigned* __restrict__ part,
    int N, int WORDS, int NT)
{
    __shared__ __align__(16) u64 sm[2 * TPB][CST];
    int b = blockIdx.x;
    int ti = 0, rowlen = NT;
    while (b >= rowlen) { b -= rowlen; ++ti; --rowlen; }
    const int tj = ti + b;
    const int kwords = WORDS / NSPLIT;           // 64
    const int kbase = blockIdx.y * kwords;

    const int tid = threadIdx.x;
    const int a = tid >> 4, bb = tid & 15;

    // stage 128 mask-rows x kwords (ulong2 per thread-iter, contiguous global)
    const int half = kwords >> 1;
    for (int idx = tid; idx < 2 * TPB * half; idx += 256) {
        const int ml = idx / half;
        const int w = (idx - ml * half) << 1;
        const int g = (ml < TPB) ? (ti * TPB + ml) : (tj * TPB + (ml - TPB));
        u64 x0 = 0, x1 = 0;
        if (g < N) {
            const u64* p = packed + (size_t)g * WORDS + kbase + w;
            x0 = p[0];
            x1 = p[1];
        }
        sm[ml][w] = x0;
        sm[ml][w + 1] = x1;
    }
    __syncthreads();

    unsigned acc[4][4] = {};
    #pragma unroll 4
    for (int w = 0; w < kwords; w += 2) {
        u64 pi0[4], pi1[4], pj0[4], pj1[4];
        #pragma unroll
        for (int t = 0; t < 4; ++t) {
            const ulonglong2 q = *reinterpret_cast<const ulonglong2*>(&sm[4 * a + t][w]);
            pi0[t] = q.x; pi1[t] = q.y;
        }
        #pragma unroll
        for (int s = 0; s < 4; ++s) {
            const ulonglong2 q = *reinterpret_cast<const ulonglong2*>(&sm[TPB + bb + 16 * s][w]);
            pj0[s] = q.x; pj1[s] = q.y;
        }
        #pragma unroll
        for (int t = 0; t < 4; ++t)
            #pragma unroll
            for (int s = 0; s < 4; ++s)
                acc[t][s] += (unsigned)__popcll(pi0[t] & pj0[s])
                           + (unsigned)__popcll(pi1[t] & pj1[s]);
    }
    #pragma unroll
    for (int t = 0; t < 4; ++t)
        #pragma unroll
        for (int s = 0; s < 4; ++s) {
            const int gi = ti * TPB + 4 * a + t;
            const int gj = tj * TPB + bb + 16 * s;
            if (gj < N && gi < gj)
                part[((size_t)gi * N + gj) * NSPLIT + blockIdx.y] = acc[t][s];
        }
}

__device__ __forceinline__ unsigned fold16(const unsigned* __restrict__ p) {
    const uint4* q = reinterpret_cast<const uint4*>(p);
    unsigned s = 0;
    #pragma unroll
    for (int k = 0; k < 4; ++k) {
        const uint4 v = q[k];
        s += v.x + v.y + v.z + v.w;
    }
    return s;
}

// ---------------------------------------------------------------------------
// K3: comp (by ORIGINAL index): comp[b] = max over a with better(a,b) and
// label match of iou(a,b). Equals reference comp at sorted slot rank(b).
// ---------------------------------------------------------------------------
__global__ __launch_bounds__(256) void k_comp(
    const unsigned* __restrict__ part, const float* __restrict__ score,
    const float* __restrict__ sum, const int* __restrict__ labels,
    float* __restrict__ comp, int N)
{
    const int bI = blockIdx.x;
    const float sb = score[bI], sub = sum[bI];
    const int lb = labels[bI];
    const int tid = threadIdx.x;
    float m = 0.0f;
    for (int a = tid; a < N; a += 256) {
        if (a == bI || labels[a] != lb) continue;
        const float sa = score[a];
        if (!better(sa, a, sb, bI)) continue;
        const int lo = a < bI ? a : bI, hi = a < bI ? bI : a;
        const float inter = (float)fold16(part + ((size_t)lo * N + hi) * NSPLIT);
        const float un = sum[a] + sub - inter;
        m = fmaxf(m, inter / fmaxf(un, 1.0f));
    }
    for (int off = 32; off > 0; off >>= 1) m = fmaxf(m, __shfl_down(m, off));
    __shared__ float lm[4];
    const int wave = tid >> 6, lane = tid & 63;
    if (lane == 0) lm[wave] = m;
    __syncthreads();
    if (tid == 0) comp[bI] = fmaxf(fmaxf(lm[0], lm[1]), fmaxf(lm[2], lm[3]));
}

// ---------------------------------------------------------------------------
// K4: final. For original b: m = max over ALL a of (d(a->b)^2 - comp[a]^2),
// d = (better(a,b) && label match) ? iou(a,b) : 0 (covers the reference's
// full-column max incl. zero entries). rank(b) = #better(a,b) computed in
// the same loop; out[rank(b)] = score[b]*exp(-sigma*m). Ranks are a
// permutation -> every out slot written exactly once.
// ---------------------------------------------------------------------------
__global__ __launch_bounds__(256) void k_final(
    const unsigned* __restrict__ part, const float* __restrict__ score,
    const float* __restrict__ sum, const int* __restrict__ labels,
    const float* __restrict__ comp, float* __restrict__ out, int N)
{
    const int bI = blockIdx.x;
    const float sb = score[bI], sub = sum[bI];
    const int lb = labels[bI];
    const int tid = threadIdx.x;
    float m = -3.0e38f;
    int r = 0;
    for (int a = tid; a < N; a += 256) {
        const float sa = score[a];
        const bool bet = (a != bI) && better(sa, a, sb, bI);
        r += (int)bet;
        float d = 0.0f;
        if (bet && labels[a] == lb) {
            const int lo = a < bI ? a : bI, hi = a < bI ? bI : a;
            const float inter = (float)fold16(part + ((size_t)lo * N + hi) * NSPLIT);
            const float un = sum[a] + sub - inter;
            d = inter / fmaxf(un, 1.0f);
        }
        const float ca = comp[a];
        m = fmaxf(m, d * d - ca * ca);
    }
    for (int off = 32; off > 0; off >>= 1) {
        m = fmaxf(m, __shfl_down(m, off));
        r += __shfl_down(r, off);
    }
    __shared__ float lm[4];
    __shared__ int lr[4];
    const int wave = tid >> 6, lane = tid & 63;
    if (lane == 0) { lm[wave] = m; lr[wave] = r; }
    __syncthreads();
    if (tid == 0) {
        const float mm = fmaxf(fmaxf(lm[0], lm[1]), fmaxf(lm[2], lm[3]));
        const int rank = lr[0] + lr[1] + lr[2] + lr[3];
        out[rank] = sb * expf(-SIGMA * mm);
    }
}

extern "C" void kernel_launch(void* const* d_in, const int* in_sizes, int n_in,
                              void* d_out, int out_size, void* d_ws, size_t ws_size,
                              hipStream_t stream)
{
    const float* preds  = (const float*)d_in[0];
    const float* cate   = (const float*)d_in[1];
    const int*   labels = (const int*)d_in[2];
    float* out = (float*)d_out;

    const int N = in_sizes[1];
    const int HW = in_sizes[0] / N;
    const int WORDS = HW >> 6;

    char* ws = (char*)d_ws;
    size_t off = 0;
    auto take = [&](size_t bytes) -> void* {
        void* p = ws + off;
        off = (off + bytes + 255) & ~(size_t)255;
        return p;
    };
    u64*      packed = (u64*)     take((size_t)N * WORDS * sizeof(u64));            // ~4.1 MB
    float*    score  = (float*)   take((size_t)N * sizeof(float));
    float*    sum    = (float*)   take((size_t)N * sizeof(float));
    float*    comp   = (float*)   take((size_t)N * sizeof(float));
    unsigned* part   = (unsigned*)take((size_t)N * N * NSPLIT * sizeof(unsigned));  // ~16 MB
    (void)ws_size; (void)n_in; (void)out_size;

    k_pack<<<N, 512, 0, stream>>>(preds, cate, packed, score, sum, HW);

    const int NT = (N + TPB - 1) / TPB;
    dim3 grid(NT * (NT + 1) / 2, NSPLIT);
    k_inter<<<grid, 256, 0, stream>>>(packed, part, N, WORDS, NT);

    k_comp<<<N, 256, 0, stream>>>(part, score, sum, labels, comp, N);

    k_final<<<N, 256, 0, stream>>>(part, score, sum, labels, comp, out, N);
}

// Round 5
// 244.057 us; speedup vs baseline: 1.8412x; 1.0059x over previous
//
#include <hip/hip_runtime.h>
#include <cstdint>

typedef unsigned long long u64;

#define THRESH 0.5f
#define SIGMA 2.0f
#define TPB 64      // pair-tile dim (64x64 pairs per tile)
#define NSPLIT 16   // K splits per tile (1024 words / 16 = 64-word chunks)
#define CST 66      // LDS row stride (u64): 528B rows -> 16B aligned, reads <=2-way (free)
#define MAXN 512    // LDS finalize capacity (N=500)

// better(a,b): does a precede b in the reference's stable descending sort?
__device__ __forceinline__ bool better(float sa, int a, float sb, int b) {
    return (sa > sb) || (sa == sb && a < b);
}

// ---------------------------------------------------------------------------
// K1: 4 blocks per mask (2000 blocks x 256 thr, ~7.8 blocks/CU). Per iter each
// lane issues FOUR back-to-back float4 loads (4 KB in flight per wave) before
// any dependent compute -> latency-hidden HBM stream. Binarize + bit-pack via
// 64-lane __ballot (fixed pixel permutation, same for all masks ->
// popcount(AND) intersections exact). fp64 partial soft-sums per task;
// finalized redundantly (deterministically) in K3/K4.
// ---------------------------------------------------------------------------
__global__ __launch_bounds__(256) void k_pack(
    const float* __restrict__ preds, u64* __restrict__ packed,
    double* __restrict__ pssum, int* __restrict__ pcnt, int HW)
{
    const int task = blockIdx.x;
    const int i = task >> 2, sub = task & 3;
    const int seg = HW >> 2;                      // 16384 px
    const float* src = preds + (size_t)i * HW + (size_t)sub * seg;
    u64* dst = packed + (size_t)i * (HW >> 6) + (size_t)sub * (seg >> 6);
    const int tid = threadIdx.x;
    const int wave = tid >> 6, lane = tid & 63;
    double ssum = 0.0;
    int cnt = 0;
    const int iters = seg >> 12;                  // 4096 px per block-iter
    for (int k = 0; k < iters; ++k) {
        const int base = (k << 12) + (wave << 10) + (lane << 2);
        const float4 v0 = *reinterpret_cast<const float4*>(src + base);
        const float4 v1 = *reinterpret_cast<const float4*>(src + base + 256);
        const float4 v2 = *reinterpret_cast<const float4*>(src + base + 512);
        const float4 v3 = *reinterpret_cast<const float4*>(src + base + 768);
        #pragma unroll
        for (int q = 0; q < 4; ++q) {
            const float4 v = (q == 0) ? v0 : (q == 1) ? v1 : (q == 2) ? v2 : v3;
            const bool b0 = v.x > THRESH, b1 = v.y > THRESH, b2 = v.z > THRESH, b3 = v.w > THRESH;
            const u64 m0 = __ballot(b0);
            const u64 m1 = __ballot(b1);
            const u64 m2 = __ballot(b2);
            const u64 m3 = __ballot(b3);
            if (lane < 4) {
                const u64 m = (lane == 0) ? m0 : (lane == 1) ? m1 : (lane == 2) ? m2 : m3;
                dst[(k << 6) + (wave << 4) + (q << 2) + lane] = m;
            }
            cnt += (int)b0 + (int)b1 + (int)b2 + (int)b3;
            ssum += (b0 ? (double)v.x : 0.0) + (b1 ? (double)v.y : 0.0)
                  + (b2 ? (double)v.z : 0.0) + (b3 ? (double)v.w : 0.0);
        }
    }
    for (int off = 32; off > 0; off >>= 1) {
        ssum += __shfl_down(ssum, off);
        cnt  += __shfl_down(cnt, off);
    }
    __shared__ double ls[4];
    __shared__ int lc[4];
    if (lane == 0) { ls[wave] = ssum; lc[wave] = cnt; }
    __syncthreads();
    if (tid == 0) {
        pssum[task] = ls[0] + ls[1] + ls[2] + ls[3];
        pcnt[task]  = lc[0] + lc[1] + lc[2] + lc[3];
    }
}

// ---------------------------------------------------------------------------
// K2: pairwise intersections on UNSORTED pairs (sort applied logically via
// better() downstream). Grid (ntri, NSPLIT); 16x16 threads, 4x4 register
// sub-tiles; i-rows blocked (broadcast), j-rows cyclic (bb+16s) -> <=2-way
// LDS reads (free). Non-atomic per-split partials, each valid slot written
// exactly once (no memset node).
// ---------------------------------------------------------------------------
__global__ __launch_bounds__(256) void k_inter(
    const u64* __restrict__ packed, unsigned* __restrict__ part,
    int N, int WORDS, int NT)
{
    __shared__ __align__(16) u64 sm[2 * TPB][CST];
    int b = blockIdx.x;
    int ti = 0, rowlen = NT;
    while (b >= rowlen) { b -= rowlen; ++ti; --rowlen; }
    const int tj = ti + b;
    const int kwords = WORDS / NSPLIT;           // 64
    const int kbase = blockIdx.y * kwords;

    const int tid = threadIdx.x;
    const int a = tid >> 4, bb = tid & 15;

    const int half = kwords >> 1;
    for (int idx = tid; idx < 2 * TPB * half; idx += 256) {
        const int ml = idx / half;
        const int w = (idx - ml * half) << 1;
        const int g = (ml < TPB) ? (ti * TPB + ml) : (tj * TPB + (ml - TPB));
        u64 x0 = 0, x1 = 0;
        if (g < N) {
            const u64* p = packed + (size_t)g * WORDS + kbase + w;
            x0 = p[0];
            x1 = p[1];
        }
        sm[ml][w] = x0;
        sm[ml][w + 1] = x1;
    }
    __syncthreads();

    unsigned acc[4][4] = {};
    #pragma unroll 4
    for (int w = 0; w < kwords; w += 2) {
        u64 pi0[4], pi1[4], pj0[4], pj1[4];
        #pragma unroll
        for (int t = 0; t < 4; ++t) {
            const ulonglong2 q = *reinterpret_cast<const ulonglong2*>(&sm[4 * a + t][w]);
            pi0[t] = q.x; pi1[t] = q.y;
        }
        #pragma unroll
        for (int s = 0; s < 4; ++s) {
            const ulonglong2 q = *reinterpret_cast<const ulonglong2*>(&sm[TPB + bb + 16 * s][w]);
            pj0[s] = q.x; pj1[s] = q.y;
        }
        #pragma unroll
        for (int t = 0; t < 4; ++t)
            #pragma unroll
            for (int s = 0; s < 4; ++s)
                acc[t][s] += (unsigned)__popcll(pi0[t] & pj0[s])
                           + (unsigned)__popcll(pi1[t] & pj1[s]);
    }
    #pragma unroll
    for (int t = 0; t < 4; ++t)
        #pragma unroll
        for (int s = 0; s < 4; ++s) {
            const int gi = ti * TPB + 4 * a + t;
            const int gj = tj * TPB + bb + 16 * s;
            if (gj < N && gi < gj)
                part[((size_t)gi * N + gj) * NSPLIT + blockIdx.y] = acc[t][s];
        }
}

__device__ __forceinline__ unsigned fold16(const unsigned* __restrict__ p) {
    const uint4* q = reinterpret_cast<const uint4*>(p);
    unsigned s = 0;
    #pragma unroll
    for (int k = 0; k < 4; ++k) {
        const uint4 v = q[k];
        s += v.x + v.y + v.z + v.w;
    }
    return s;
}

// Deterministic score finalize into LDS (identical arithmetic order wherever
// called -> bit-identical scores across kernels).
__device__ __forceinline__ void finalize_scores(
    const double* __restrict__ pssum, const int* __restrict__ pcnt,
    const float* __restrict__ cate, const int* __restrict__ labels,
    float* s_score, float* s_sum, int* s_label, int N, int tid)
{
    for (int idx = tid; idx < N; idx += 256) {
        const double S = ((pssum[4*idx] + pssum[4*idx+1]) + pssum[4*idx+2]) + pssum[4*idx+3];
        const int C = ((pcnt[4*idx] + pcnt[4*idx+1]) + pcnt[4*idx+2]) + pcnt[4*idx+3];
        s_score[idx] = cate[idx] * (float)(S / (double)(C > 1 ? C : 1));
        s_sum[idx] = (float)C;
        s_label[idx] = labels[idx];
    }
    __syncthreads();
}

// ---------------------------------------------------------------------------
// K3: comp (by ORIGINAL index): comp[b] = max over {a: better(a,b), label
// match} of iou(a,b). Scores finalized into LDS first (cheap, redundant).
// ---------------------------------------------------------------------------
__global__ __launch_bounds__(256) void k_comp(
    const unsigned* __restrict__ part,
    const double* __restrict__ pssum, const int* __restrict__ pcnt,
    const float* __restrict__ cate, const int* __restrict__ labels,
    float* __restrict__ comp, int N)
{
    __shared__ float s_score[MAXN];
    __shared__ float s_sum[MAXN];
    __shared__ int s_label[MAXN];
    const int tid = threadIdx.x;
    finalize_scores(pssum, pcnt, cate, labels, s_score, s_sum, s_label, N, tid);

    const int bI = blockIdx.x;
    const float sb = s_score[bI], sub = s_sum[bI];
    const int lb = s_label[bI];
    float m = 0.0f;
    for (int a = tid; a < N; a += 256) {
        if (a == bI || s_label[a] != lb) continue;
        if (!better(s_score[a], a, sb, bI)) continue;
        const int lo = a < bI ? a : bI, hi = a < bI ? bI : a;
        const float inter = (float)fold16(part + ((size_t)lo * N + hi) * NSPLIT);
        const float un = s_sum[a] + sub - inter;
        m = fmaxf(m, inter / fmaxf(un, 1.0f));
    }
    for (int off = 32; off > 0; off >>= 1) m = fmaxf(m, __shfl_down(m, off));
    __shared__ float lm[4];
    const int wave = tid >> 6, lane = tid & 63;
    if (lane == 0) lm[wave] = m;
    __syncthreads();
    if (tid == 0) comp[bI] = fmaxf(fmaxf(lm[0], lm[1]), fmaxf(lm[2], lm[3]));
}

// ---------------------------------------------------------------------------
// K4: final. m = max over ALL a of (d(a->b)^2 - comp[a]^2), d = (better &&
// label match) ? iou : 0; rank(b) = #better(a,b) in the same loop;
// out[rank(b)] = score[b]*exp(-sigma*m). Ranks are a permutation.
// ---------------------------------------------------------------------------
__global__ __launch_bounds__(256) void k_final(
    const unsigned* __restrict__ part,
    const double* __restrict__ pssum, const int* __restrict__ pcnt,
    const float* __restrict__ cate, const int* __restrict__ labels,
    const float* __restrict__ comp, float* __restrict__ out, int N)
{
    __shared__ float s_score[MAXN];
    __shared__ float s_sum[MAXN];
    __shared__ int s_label[MAXN];
    const int tid = threadIdx.x;
    finalize_scores(pssum, pcnt, cate, labels, s_score, s_sum, s_label, N, tid);

    const int bI = blockIdx.x;
    const float sb = s_score[bI], sub = s_sum[bI];
    const int lb = s_label[bI];
    float m = -3.0e38f;
    int r = 0;
    for (int a = tid; a < N; a += 256) {
        const bool bet = (a != bI) && better(s_score[a], a, sb, bI);
        r += (int)bet;
        float d = 0.0f;
        if (bet && s_label[a] == lb) {
            const int lo = a < bI ? a : bI, hi = a < bI ? bI : a;
            const float inter = (float)fold16(part + ((size_t)lo * N + hi) * NSPLIT);
            const float un = s_sum[a] + sub - inter;
            d = inter / fmaxf(un, 1.0f);
        }
        const float ca = comp[a];
        m = fmaxf(m, d * d - ca * ca);
    }
    for (int off = 32; off > 0; off >>= 1) {
        m = fmaxf(m, __shfl_down(m, off));
        r += __shfl_down(r, off);
    }
    __shared__ float lm[4];
    __shared__ int lr[4];
    const int wave = tid >> 6, lane = tid & 63;
    if (lane == 0) { lm[wave] = m; lr[wave] = r; }
    __syncthreads();
    if (tid == 0) {
        const float mm = fmaxf(fmaxf(lm[0], lm[1]), fmaxf(lm[2], lm[3]));
        const int rank = lr[0] + lr[1] + lr[2] + lr[3];
        out[rank] = sb * expf(-SIGMA * mm);
    }
}

extern "C" void kernel_launch(void* const* d_in, const int* in_sizes, int n_in,
                              void* d_out, int out_size, void* d_ws, size_t ws_size,
                              hipStream_t stream)
{
    const float* preds  = (const float*)d_in[0];
    const float* cate   = (const float*)d_in[1];
    const int*   labels = (const int*)d_in[2];
    float* out = (float*)d_out;

    const int N = in_sizes[1];
    const int HW = in_sizes[0] / N;
    const int WORDS = HW >> 6;

    char* ws = (char*)d_ws;
    size_t off = 0;
    auto take = [&](size_t bytes) -> void* {
        void* p = ws + off;
        off = (off + bytes + 255) & ~(size_t)255;
        return p;
    };
    u64*      packed = (u64*)     take((size_t)N * WORDS * sizeof(u64));            // ~4.1 MB
    double*   pssum  = (double*)  take((size_t)N * 4 * sizeof(double));
    int*      pcnt   = (int*)     take((size_t)N * 4 * sizeof(int));
    float*    comp   = (float*)   take((size_t)N * sizeof(float));
    unsigned* part   = (unsigned*)take((size_t)N * N * NSPLIT * sizeof(unsigned));  // ~16 MB
    (void)ws_size; (void)n_in; (void)out_size;

    k_pack<<<N * 4, 256, 0, stream>>>(preds, packed, pssum, pcnt, HW);

    const int NT = (N + TPB - 1) / TPB;
    dim3 grid(NT * (NT + 1) / 2, NSPLIT);
    k_inter<<<grid, 256, 0, stream>>>(packed, part, N, WORDS, NT);

    k_comp<<<N, 256, 0, stream>>>(part, pssum, pcnt, cate, labels, comp, N);

    k_final<<<N, 256, 0, stream>>>(part, pssum, pcnt, cate, labels, comp, out, N);
}